// Round 1
// baseline (537.753 us; speedup 1.0000x reference)
//
#include <hip/hip_runtime.h>

// ---------------------------------------------------------------------------
// 2-layer GCN on MI355X.  Pipeline:
//   detect edge dtype -> init -> count deg -> scan (CSR rowptr) -> dinv+zero
//   -> fill CSR -> GEMM1 (x@W1) -> AGG1 (gather, +b1, relu)
//   -> GEMM2 (h@W2)  -> AGG2 (gather, +b2) -> d_out
// All fp32 (no fp32 MFMA on CDNA4; bf16 too risky vs 1e-2 absmax threshold).
// ---------------------------------------------------------------------------

// Detect whether edge_index arrived as int64 (odd int32 words are all the
// zero high-halves) or int32.  Values are < 50000 so low word suffices.
__global__ void k_detect(const int* __restrict__ e32, int* __restrict__ flag) {
    int l = threadIdx.x;                 // 0..63
    int v = e32[2 * l + 1];
    unsigned long long ball = __ballot(v == 0);
    if (l == 0) flag[0] = (ball == ~0ull) ? 1 : 0;
}

__device__ __forceinline__ int edge_at(const int* __restrict__ e32, long long idx, int is64) {
    return is64 ? e32[2 * idx] : e32[(int)idx];
}

__global__ void k_init(float* __restrict__ deg, int* __restrict__ cnt, int n) {
    int i = blockIdx.x * blockDim.x + threadIdx.x;
    if (i < n) { deg[i] = 1.0f; cnt[i] = 0; }   // deg starts at 1 (self-loop)
}

__global__ void k_count(const int* __restrict__ e32, const int* __restrict__ flag,
                        float* __restrict__ deg, int* __restrict__ cnt, int E) {
    int is64 = flag[0];
    int e = blockIdx.x * blockDim.x + threadIdx.x;
    if (e < E) {
        int d = edge_at(e32, (long long)E + e, is64);   // dst row = second half
        atomicAdd(&deg[d], 1.0f);
        atomicAdd(&cnt[d], 1);
    }
}

#define SCAN_T 1024
__global__ __launch_bounds__(SCAN_T) void k_scan(const int* __restrict__ cnt,
                                                 int* __restrict__ rowptr, int n, int E) {
    __shared__ int sums[SCAN_T];
    int t = threadIdx.x;
    int C = (n + SCAN_T - 1) / SCAN_T;
    int lo = t * C;
    int hi = lo + C; if (hi > n) hi = n;
    int s = 0;
    for (int i = lo; i < hi; ++i) s += cnt[i];
    sums[t] = s;
    __syncthreads();
    for (int off = 1; off < SCAN_T; off <<= 1) {     // Hillis-Steele inclusive
        int v = (t >= off) ? sums[t - off] : 0;
        __syncthreads();
        sums[t] += v;
        __syncthreads();
    }
    int run = sums[t] - s;                           // exclusive base for chunk
    for (int i = lo; i < hi; ++i) { rowptr[i] = run; run += cnt[i]; }
    if (t == 0) rowptr[n] = E;
}

__global__ void k_dinv_zero(float* __restrict__ deg, int* __restrict__ cnt, int n) {
    int i = blockIdx.x * blockDim.x + threadIdx.x;
    if (i < n) { deg[i] = rsqrtf(deg[i]); cnt[i] = 0; }  // deg >= 1 always
}

__global__ void k_fill(const int* __restrict__ e32, const int* __restrict__ flag,
                       const int* __restrict__ rowptr, int* __restrict__ cursor,
                       int* __restrict__ esrc, int E) {
    int is64 = flag[0];
    int e = blockIdx.x * blockDim.x + threadIdx.x;
    if (e < E) {
        int s = edge_at(e32, e, is64);
        int d = edge_at(e32, (long long)E + e, is64);
        int pos = rowptr[d] + atomicAdd(&cursor[d], 1);
        esrc[pos] = s;
    }
}

// GEMM1: X[n,256] @ W[256,128] -> H[n,128].  BM=64, BN=128, BK=32, 256 thr.
__global__ __launch_bounds__(256) void k_gemm1(const float* __restrict__ X,
                                               const float* __restrict__ W,
                                               float* __restrict__ H, int n) {
    __shared__ float As[32][65];    // transposed [k][m], +1 pad
    __shared__ float Bs[32][128];
    int t = threadIdx.x;
    int ty = t >> 4, tx = t & 15;   // 16 x 16 thread grid, each 4 rows x 8 cols
    int row0 = blockIdx.x * 64;
    float acc[4][8] = {};
    for (int k0 = 0; k0 < 256; k0 += 32) {
        {   // A tile: 64 rows x 32 k, 2 x float4 per thread
            int r = t >> 3;            // 0..31
            int kk = (t & 7) * 4;      // 0..28
            #pragma unroll
            for (int p = 0; p < 2; ++p) {
                int rr = r + p * 32;
                int grow = row0 + rr;
                float4 v = {0.f, 0.f, 0.f, 0.f};
                if (grow < n) v = *reinterpret_cast<const float4*>(&X[(size_t)grow * 256 + k0 + kk]);
                As[kk + 0][rr] = v.x; As[kk + 1][rr] = v.y;
                As[kk + 2][rr] = v.z; As[kk + 3][rr] = v.w;
            }
        }
        {   // B tile: 32 k x 128 cols, 4 x float4 per thread
            int kk = t >> 5;           // 0..7
            int c  = (t & 31) * 4;     // 0..124
            #pragma unroll
            for (int p = 0; p < 4; ++p) {
                int krow = kk + p * 8;
                *reinterpret_cast<float4*>(&Bs[krow][c]) =
                    *reinterpret_cast<const float4*>(&W[(k0 + krow) * 128 + c]);
            }
        }
        __syncthreads();
        #pragma unroll
        for (int k = 0; k < 32; ++k) {
            float a[4];
            #pragma unroll
            for (int i = 0; i < 4; ++i) a[i] = As[k][ty * 4 + i];
            float4 b0 = *reinterpret_cast<const float4*>(&Bs[k][tx * 8]);
            float4 b1 = *reinterpret_cast<const float4*>(&Bs[k][tx * 8 + 4]);
            float b[8] = {b0.x, b0.y, b0.z, b0.w, b1.x, b1.y, b1.z, b1.w};
            #pragma unroll
            for (int i = 0; i < 4; ++i)
                #pragma unroll
                for (int j = 0; j < 8; ++j)
                    acc[i][j] += a[i] * b[j];
        }
        __syncthreads();
    }
    #pragma unroll
    for (int i = 0; i < 4; ++i) {
        int grow = row0 + ty * 4 + i;
        if (grow < n) {
            float4 o0 = {acc[i][0], acc[i][1], acc[i][2], acc[i][3]};
            float4 o1 = {acc[i][4], acc[i][5], acc[i][6], acc[i][7]};
            *reinterpret_cast<float4*>(&H[(size_t)grow * 128 + tx * 8])     = o0;
            *reinterpret_cast<float4*>(&H[(size_t)grow * 128 + tx * 8 + 4]) = o1;
        }
    }
}

// AGG1: wave per node, 128 features (float2/lane).  out = relu(dinv[n]*(h[n]*dinv[n]
//       + sum_s h[s]*dinv[s]) + b1)
__global__ __launch_bounds__(256) void k_agg1(const float* __restrict__ H,
                                              const float* __restrict__ dinv,
                                              const int* __restrict__ rowptr,
                                              const int* __restrict__ esrc,
                                              const float* __restrict__ b1,
                                              float* __restrict__ O, int n) {
    int wave = threadIdx.x >> 6;
    int lane = threadIdx.x & 63;
    int node = blockIdx.x * 4 + wave;
    if (node >= n) return;
    int f = lane * 2;
    float dn = dinv[node];
    float2 h = *reinterpret_cast<const float2*>(&H[(size_t)node * 128 + f]);
    float acc0 = h.x * dn, acc1 = h.y * dn;
    int lo = rowptr[node], hi = rowptr[node + 1];
    for (int e = lo; e < hi; ++e) {
        int s = esrc[e];
        float ds = dinv[s];
        float2 v = *reinterpret_cast<const float2*>(&H[(size_t)s * 128 + f]);
        acc0 += v.x * ds;
        acc1 += v.y * ds;
    }
    acc0 = acc0 * dn + b1[f];
    acc1 = acc1 * dn + b1[f + 1];
    O[(size_t)node * 128 + f]     = fmaxf(acc0, 0.f);
    O[(size_t)node * 128 + f + 1] = fmaxf(acc1, 0.f);
}

// GEMM2: A[n,128] @ W2[128,64] -> H[n,64].  W2 fully LDS-resident.
__global__ __launch_bounds__(256) void k_gemm2(const float* __restrict__ A,
                                               const float* __restrict__ W,
                                               float* __restrict__ H, int n) {
    __shared__ float As[32][65];
    __shared__ float Bs[128][64];
    int t = threadIdx.x;
    int ty = t >> 4, tx = t & 15;   // each thread: 4 rows x 4 cols
    int row0 = blockIdx.x * 64;
    {   // load all of W2: 8192 floats = 2048 float4
        const float4* Wv = reinterpret_cast<const float4*>(W);
        float4* Bv = reinterpret_cast<float4*>(&Bs[0][0]);
        for (int i = t; i < 2048; i += 256) Bv[i] = Wv[i];
    }
    float acc[4][4] = {};
    for (int k0 = 0; k0 < 128; k0 += 32) {
        __syncthreads();    // protect previous iter's As reads (and Bs load, iter 0)
        {
            int r = t >> 3;
            int kk = (t & 7) * 4;
            #pragma unroll
            for (int p = 0; p < 2; ++p) {
                int rr = r + p * 32;
                int grow = row0 + rr;
                float4 v = {0.f, 0.f, 0.f, 0.f};
                if (grow < n) v = *reinterpret_cast<const float4*>(&A[(size_t)grow * 128 + k0 + kk]);
                As[kk + 0][rr] = v.x; As[kk + 1][rr] = v.y;
                As[kk + 2][rr] = v.z; As[kk + 3][rr] = v.w;
            }
        }
        __syncthreads();
        #pragma unroll
        for (int k = 0; k < 32; ++k) {
            float a[4];
            #pragma unroll
            for (int i = 0; i < 4; ++i) a[i] = As[k][ty * 4 + i];
            float4 b = *reinterpret_cast<const float4*>(&Bs[k0 + k][tx * 4]);
            #pragma unroll
            for (int i = 0; i < 4; ++i) {
                acc[i][0] += a[i] * b.x; acc[i][1] += a[i] * b.y;
                acc[i][2] += a[i] * b.z; acc[i][3] += a[i] * b.w;
            }
        }
    }
    #pragma unroll
    for (int i = 0; i < 4; ++i) {
        int grow = row0 + ty * 4 + i;
        if (grow < n) {
            float4 o = {acc[i][0], acc[i][1], acc[i][2], acc[i][3]};
            *reinterpret_cast<float4*>(&H[(size_t)grow * 64 + tx * 4]) = o;
        }
    }
}

// AGG2: wave per node, 64 features (1 float/lane), += b2 -> d_out.
__global__ __launch_bounds__(256) void k_agg2(const float* __restrict__ H,
                                              const float* __restrict__ dinv,
                                              const int* __restrict__ rowptr,
                                              const int* __restrict__ esrc,
                                              const float* __restrict__ b2,
                                              float* __restrict__ O, int n) {
    int wave = threadIdx.x >> 6;
    int lane = threadIdx.x & 63;
    int node = blockIdx.x * 4 + wave;
    if (node >= n) return;
    float dn = dinv[node];
    float acc = H[(size_t)node * 64 + lane] * dn;
    int lo = rowptr[node], hi = rowptr[node + 1];
    for (int e = lo; e < hi; ++e) {
        int s = esrc[e];
        acc += H[(size_t)s * 64 + lane] * dinv[s];
    }
    O[(size_t)node * 64 + lane] = acc * dn + b2[lane];
}

extern "C" void kernel_launch(void* const* d_in, const int* in_sizes, int n_in,
                              void* d_out, int out_size, void* d_ws, size_t ws_size,
                              hipStream_t stream) {
    const float* x   = (const float*)d_in[0];
    const int*   e32 = (const int*)d_in[1];
    const float* W1  = (const float*)d_in[2];
    const float* b1  = (const float*)d_in[3];
    const float* W2  = (const float*)d_in[4];
    const float* b2  = (const float*)d_in[5];
    float* out = (float*)d_out;

    const int HID  = in_sizes[3];           // 128
    const int FIN  = in_sizes[2] / HID;     // 256
    const int N    = in_sizes[0] / FIN;     // 50000
    const int E    = in_sizes[1] / 2;       // 800000
    (void)n_in; (void)out_size; (void)ws_size;

    char* ws = (char*)d_ws;
    size_t off = 0;
    auto take = [&](size_t bytes) -> void* {
        void* p = ws + off;
        off += (bytes + 255) & ~(size_t)255;
        return p;
    };
    int*   flag   = (int*)  take(4);
    float* dinv   = (float*)take((size_t)N * 4);
    int*   cnt    = (int*)  take((size_t)N * 4);
    int*   rowptr = (int*)  take((size_t)(N + 1) * 4);
    int*   esrc   = (int*)  take((size_t)E * 4);
    float* h1     = (float*)take((size_t)N * HID * 4);
    float* agg1   = (float*)take((size_t)N * HID * 4);
    float* h2     = h1;   // h1 dead after AGG1; reuse for layer-2 transform

    int gN  = (N + 255) / 256;
    int gE  = (E + 255) / 256;
    int gM  = (N + 63) / 64;
    int gAg = (N + 3) / 4;

    k_detect   <<<1,   64,  0, stream>>>(e32, flag);
    k_init     <<<gN,  256, 0, stream>>>(dinv, cnt, N);
    k_count    <<<gE,  256, 0, stream>>>(e32, flag, dinv, cnt, E);
    k_scan     <<<1, SCAN_T, 0, stream>>>(cnt, rowptr, N, E);
    k_dinv_zero<<<gN,  256, 0, stream>>>(dinv, cnt, N);
    k_fill     <<<gE,  256, 0, stream>>>(e32, flag, rowptr, cnt, esrc, E);
    k_gemm1    <<<gM,  256, 0, stream>>>(x, W1, h1, N);
    k_agg1     <<<gAg, 256, 0, stream>>>(h1, dinv, rowptr, esrc, b1, agg1, N);
    k_gemm2    <<<gM,  256, 0, stream>>>(agg1, W2, h2, N);
    k_agg2     <<<gAg, 256, 0, stream>>>(h2, dinv, rowptr, esrc, b2, out, N);
}

// Round 3
// 413.513 us; speedup vs baseline: 1.3005x; 1.3005x over previous
//
#include <hip/hip_runtime.h>

// ---------------------------------------------------------------------------
// 2-layer GCN on MI355X.  Pipeline:
//   detect edge dtype -> init -> count deg (int only) -> scan (CSR rowptr)
//   -> dinv from cnt + zero cnt -> fill CSR w/ packed (src, dinv[src])
//   -> GEMM1 (x@W1) -> AGG1 (gather, +b1, relu)
//   -> GEMM2 (h@W2) -> AGG2 (gather, +b2) -> d_out
// All fp32 (no fp32 MFMA on CDNA4; bf16 risky vs 1e-2 absmax threshold).
// Round-2 change: agg kernels restructured for memory-level parallelism
// (half/quarter-wave per node, float4 lanes, 4-wide edge unroll, packed
// per-edge (src,norm) metadata) -- was latency-bound at 30% HBM BW.
// Round-3: resubmit (round-2 bench was an infra failure, no data).
// ---------------------------------------------------------------------------

__global__ void k_detect(const int* __restrict__ e32, int* __restrict__ flag) {
    int l = threadIdx.x;                 // 0..63
    int v = e32[2 * l + 1];
    unsigned long long ball = __ballot(v == 0);
    if (l == 0) flag[0] = (ball == ~0ull) ? 1 : 0;
}

__device__ __forceinline__ int edge_at(const int* __restrict__ e32, long long idx, int is64) {
    return is64 ? e32[2 * idx] : e32[(int)idx];
}

__global__ void k_init(int* __restrict__ cnt, int n) {
    int i = blockIdx.x * blockDim.x + threadIdx.x;
    if (i < n) cnt[i] = 0;
}

__global__ void k_count(const int* __restrict__ e32, const int* __restrict__ flag,
                        int* __restrict__ cnt, int E) {
    int is64 = flag[0];
    int e = blockIdx.x * blockDim.x + threadIdx.x;
    if (e < E) {
        int d = edge_at(e32, (long long)E + e, is64);   // dst row = second half
        atomicAdd(&cnt[d], 1);
    }
}

#define SCAN_T 1024
__global__ __launch_bounds__(SCAN_T) void k_scan(const int* __restrict__ cnt,
                                                 int* __restrict__ rowptr, int n, int E) {
    __shared__ int sums[SCAN_T];
    int t = threadIdx.x;
    int C = (n + SCAN_T - 1) / SCAN_T;
    int lo = t * C;
    int hi = lo + C; if (hi > n) hi = n;
    int s = 0;
    for (int i = lo; i < hi; ++i) s += cnt[i];
    sums[t] = s;
    __syncthreads();
    for (int off = 1; off < SCAN_T; off <<= 1) {     // Hillis-Steele inclusive
        int v = (t >= off) ? sums[t - off] : 0;
        __syncthreads();
        sums[t] += v;
        __syncthreads();
    }
    int run = sums[t] - s;                           // exclusive base for chunk
    for (int i = lo; i < hi; ++i) { rowptr[i] = run; run += cnt[i]; }
    if (t == 0) rowptr[n] = E;
}

// dinv = rsqrt(1 + cnt)  (self-loop included); re-zero cnt for use as cursor.
__global__ void k_dinv_zero(const int* __restrict__ cntin, float* __restrict__ dinv,
                            int* __restrict__ cnt, int n) {
    int i = blockIdx.x * blockDim.x + threadIdx.x;
    if (i < n) { dinv[i] = rsqrtf(1.0f + (float)cntin[i]); cnt[i] = 0; }
}

// CSR fill with packed metadata: ep[pos] = { bitcast(src), dinv[src] }.
__global__ void k_fill(const int* __restrict__ e32, const int* __restrict__ flag,
                       const int* __restrict__ rowptr, int* __restrict__ cursor,
                       const float* __restrict__ dinv, float2* __restrict__ ep, int E) {
    int is64 = flag[0];
    int e = blockIdx.x * blockDim.x + threadIdx.x;
    if (e < E) {
        int s = edge_at(e32, e, is64);
        int d = edge_at(e32, (long long)E + e, is64);
        int pos = rowptr[d] + atomicAdd(&cursor[d], 1);
        ep[pos] = make_float2(__int_as_float(s), dinv[s]);
    }
}

// GEMM1: X[n,256] @ W[256,128] -> H[n,128].  BM=64, BN=128, BK=32, 256 thr.
__global__ __launch_bounds__(256) void k_gemm1(const float* __restrict__ X,
                                               const float* __restrict__ W,
                                               float* __restrict__ H, int n) {
    __shared__ float As[32][68];    // transposed [k][m]; 68*4=272 B stride (16B-aligned)
    __shared__ float Bs[32][128];
    int t = threadIdx.x;
    int ty = t >> 4, tx = t & 15;   // 16 x 16 thread grid, each 4 rows x 8 cols
    int row0 = blockIdx.x * 64;
    float acc[4][8] = {};
    for (int k0 = 0; k0 < 256; k0 += 32) {
        {   // A tile: 64 rows x 32 k, 2 x float4 per thread
            int r = t >> 3;            // 0..31
            int kk = (t & 7) * 4;      // 0..28
            #pragma unroll
            for (int p = 0; p < 2; ++p) {
                int rr = r + p * 32;
                int grow = row0 + rr;
                float4 v = {0.f, 0.f, 0.f, 0.f};
                if (grow < n) v = *reinterpret_cast<const float4*>(&X[(size_t)grow * 256 + k0 + kk]);
                As[kk + 0][rr] = v.x; As[kk + 1][rr] = v.y;
                As[kk + 2][rr] = v.z; As[kk + 3][rr] = v.w;
            }
        }
        {   // B tile: 32 k x 128 cols, 4 x float4 per thread
            int kk = t >> 5;           // 0..7
            int c  = (t & 31) * 4;     // 0..124
            #pragma unroll
            for (int p = 0; p < 4; ++p) {
                int krow = kk + p * 8;
                *reinterpret_cast<float4*>(&Bs[krow][c]) =
                    *reinterpret_cast<const float4*>(&W[(k0 + krow) * 128 + c]);
            }
        }
        __syncthreads();
        #pragma unroll
        for (int k = 0; k < 32; ++k) {
            float4 av = *reinterpret_cast<const float4*>(&As[k][ty * 4]);
            float a[4] = {av.x, av.y, av.z, av.w};
            float4 b0 = *reinterpret_cast<const float4*>(&Bs[k][tx * 8]);
            float4 b1 = *reinterpret_cast<const float4*>(&Bs[k][tx * 8 + 4]);
            float b[8] = {b0.x, b0.y, b0.z, b0.w, b1.x, b1.y, b1.z, b1.w};
            #pragma unroll
            for (int i = 0; i < 4; ++i)
                #pragma unroll
                for (int j = 0; j < 8; ++j)
                    acc[i][j] += a[i] * b[j];
        }
        __syncthreads();
    }
    #pragma unroll
    for (int i = 0; i < 4; ++i) {
        int grow = row0 + ty * 4 + i;
        if (grow < n) {
            float4 o0 = {acc[i][0], acc[i][1], acc[i][2], acc[i][3]};
            float4 o1 = {acc[i][4], acc[i][5], acc[i][6], acc[i][7]};
            *reinterpret_cast<float4*>(&H[(size_t)grow * 128 + tx * 8])     = o0;
            *reinterpret_cast<float4*>(&H[(size_t)grow * 128 + tx * 8 + 4]) = o1;
        }
    }
}

// AGG1: half-wave (32 lanes x float4) per node, 128 features.
// out = relu(dn*(h[n]*dn + sum_s h[s]*dinv[s]) + b1)
__global__ __launch_bounds__(256) void k_agg1(const float* __restrict__ H,
                                              const float* __restrict__ dinv,
                                              const int* __restrict__ rowptr,
                                              const float2* __restrict__ ep,
                                              const float* __restrict__ b1,
                                              float* __restrict__ O, int n) {
    int half = threadIdx.x >> 5;        // 0..7
    int lane = threadIdx.x & 31;
    int node = blockIdx.x * 8 + half;
    if (node >= n) return;
    int f = lane * 4;
    float dn = dinv[node];
    float4 acc = *reinterpret_cast<const float4*>(&H[(size_t)node * 128 + f]);
    acc.x *= dn; acc.y *= dn; acc.z *= dn; acc.w *= dn;
    int lo = rowptr[node], hi = rowptr[node + 1];
    int e = lo;
    for (; e + 4 <= hi; e += 4) {       // 4 row loads in flight per half-wave
        float2 m0 = ep[e + 0], m1 = ep[e + 1], m2 = ep[e + 2], m3 = ep[e + 3];
        const float4 v0 = *reinterpret_cast<const float4*>(&H[(size_t)__float_as_int(m0.x) * 128 + f]);
        const float4 v1 = *reinterpret_cast<const float4*>(&H[(size_t)__float_as_int(m1.x) * 128 + f]);
        const float4 v2 = *reinterpret_cast<const float4*>(&H[(size_t)__float_as_int(m2.x) * 128 + f]);
        const float4 v3 = *reinterpret_cast<const float4*>(&H[(size_t)__float_as_int(m3.x) * 128 + f]);
        acc.x += v0.x * m0.y + v1.x * m1.y + v2.x * m2.y + v3.x * m3.y;
        acc.y += v0.y * m0.y + v1.y * m1.y + v2.y * m2.y + v3.y * m3.y;
        acc.z += v0.z * m0.y + v1.z * m1.y + v2.z * m2.y + v3.z * m3.y;
        acc.w += v0.w * m0.y + v1.w * m1.y + v2.w * m2.y + v3.w * m3.y;
    }
    for (; e < hi; ++e) {
        float2 m = ep[e];
        const float4 v = *reinterpret_cast<const float4*>(&H[(size_t)__float_as_int(m.x) * 128 + f]);
        acc.x += v.x * m.y; acc.y += v.y * m.y;
        acc.z += v.z * m.y; acc.w += v.w * m.y;
    }
    float4 bv = *reinterpret_cast<const float4*>(&b1[f]);
    acc.x = fmaxf(acc.x * dn + bv.x, 0.f);
    acc.y = fmaxf(acc.y * dn + bv.y, 0.f);
    acc.z = fmaxf(acc.z * dn + bv.z, 0.f);
    acc.w = fmaxf(acc.w * dn + bv.w, 0.f);
    *reinterpret_cast<float4*>(&O[(size_t)node * 128 + f]) = acc;
}

// GEMM2: A[n,128] @ W2[128,64] -> H[n,64].  W2 fully LDS-resident.
__global__ __launch_bounds__(256) void k_gemm2(const float* __restrict__ A,
                                               const float* __restrict__ W,
                                               float* __restrict__ H, int n) {
    __shared__ float As[32][68];
    __shared__ float Bs[128][64];
    int t = threadIdx.x;
    int ty = t >> 4, tx = t & 15;   // each thread: 4 rows x 4 cols
    int row0 = blockIdx.x * 64;
    {   // load all of W2: 8192 floats = 2048 float4
        const float4* Wv = reinterpret_cast<const float4*>(W);
        float4* Bv = reinterpret_cast<float4*>(&Bs[0][0]);
        for (int i = t; i < 2048; i += 256) Bv[i] = Wv[i];
    }
    float acc[4][4] = {};
    for (int k0 = 0; k0 < 128; k0 += 32) {
        __syncthreads();    // protect previous iter's As reads (and Bs load, iter 0)
        {
            int r = t >> 3;
            int kk = (t & 7) * 4;
            #pragma unroll
            for (int p = 0; p < 2; ++p) {
                int rr = r + p * 32;
                int grow = row0 + rr;
                float4 v = {0.f, 0.f, 0.f, 0.f};
                if (grow < n) v = *reinterpret_cast<const float4*>(&A[(size_t)grow * 128 + k0 + kk]);
                As[kk + 0][rr] = v.x; As[kk + 1][rr] = v.y;
                As[kk + 2][rr] = v.z; As[kk + 3][rr] = v.w;
            }
        }
        __syncthreads();
        #pragma unroll
        for (int k = 0; k < 32; ++k) {
            float4 av = *reinterpret_cast<const float4*>(&As[k][ty * 4]);
            float a[4] = {av.x, av.y, av.z, av.w};
            float4 b = *reinterpret_cast<const float4*>(&Bs[k0 + k][tx * 4]);
            #pragma unroll
            for (int i = 0; i < 4; ++i) {
                acc[i][0] += a[i] * b.x; acc[i][1] += a[i] * b.y;
                acc[i][2] += a[i] * b.z; acc[i][3] += a[i] * b.w;
            }
        }
    }
    #pragma unroll
    for (int i = 0; i < 4; ++i) {
        int grow = row0 + ty * 4 + i;
        if (grow < n) {
            float4 o = {acc[i][0], acc[i][1], acc[i][2], acc[i][3]};
            *reinterpret_cast<float4*>(&H[(size_t)grow * 64 + tx * 4]) = o;
        }
    }
}

// AGG2: quarter-wave (16 lanes x float4) per node, 64 features, += b2 -> d_out.
__global__ __launch_bounds__(256) void k_agg2(const float* __restrict__ H,
                                              const float* __restrict__ dinv,
                                              const int* __restrict__ rowptr,
                                              const float2* __restrict__ ep,
                                              const float* __restrict__ b2,
                                              float* __restrict__ O, int n) {
    int q    = threadIdx.x >> 4;        // 0..15
    int lane = threadIdx.x & 15;
    int node = blockIdx.x * 16 + q;
    if (node >= n) return;
    int f = lane * 4;
    float dn = dinv[node];
    float4 acc = *reinterpret_cast<const float4*>(&H[(size_t)node * 64 + f]);
    acc.x *= dn; acc.y *= dn; acc.z *= dn; acc.w *= dn;
    int lo = rowptr[node], hi = rowptr[node + 1];
    int e = lo;
    for (; e + 4 <= hi; e += 4) {
        float2 m0 = ep[e + 0], m1 = ep[e + 1], m2 = ep[e + 2], m3 = ep[e + 3];
        const float4 v0 = *reinterpret_cast<const float4*>(&H[(size_t)__float_as_int(m0.x) * 64 + f]);
        const float4 v1 = *reinterpret_cast<const float4*>(&H[(size_t)__float_as_int(m1.x) * 64 + f]);
        const float4 v2 = *reinterpret_cast<const float4*>(&H[(size_t)__float_as_int(m2.x) * 64 + f]);
        const float4 v3 = *reinterpret_cast<const float4*>(&H[(size_t)__float_as_int(m3.x) * 64 + f]);
        acc.x += v0.x * m0.y + v1.x * m1.y + v2.x * m2.y + v3.x * m3.y;
        acc.y += v0.y * m0.y + v1.y * m1.y + v2.y * m2.y + v3.y * m3.y;
        acc.z += v0.z * m0.y + v1.z * m1.y + v2.z * m2.y + v3.z * m3.y;
        acc.w += v0.w * m0.y + v1.w * m1.y + v2.w * m2.y + v3.w * m3.y;
    }
    for (; e < hi; ++e) {
        float2 m = ep[e];
        const float4 v = *reinterpret_cast<const float4*>(&H[(size_t)__float_as_int(m.x) * 64 + f]);
        acc.x += v.x * m.y; acc.y += v.y * m.y;
        acc.z += v.z * m.y; acc.w += v.w * m.y;
    }
    float4 bv = *reinterpret_cast<const float4*>(&b2[f]);
    acc.x = acc.x * dn + bv.x;
    acc.y = acc.y * dn + bv.y;
    acc.z = acc.z * dn + bv.z;
    acc.w = acc.w * dn + bv.w;
    *reinterpret_cast<float4*>(&O[(size_t)node * 64 + f]) = acc;
}

extern "C" void kernel_launch(void* const* d_in, const int* in_sizes, int n_in,
                              void* d_out, int out_size, void* d_ws, size_t ws_size,
                              hipStream_t stream) {
    const float* x   = (const float*)d_in[0];
    const int*   e32 = (const int*)d_in[1];
    const float* W1  = (const float*)d_in[2];
    const float* b1  = (const float*)d_in[3];
    const float* W2  = (const float*)d_in[4];
    const float* b2  = (const float*)d_in[5];
    float* out = (float*)d_out;

    const int HID  = in_sizes[3];           // 128
    const int FIN  = in_sizes[2] / HID;     // 256
    const int N    = in_sizes[0] / FIN;     // 50000
    const int E    = in_sizes[1] / 2;       // 800000
    (void)n_in; (void)out_size; (void)ws_size;

    char* ws = (char*)d_ws;
    size_t off = 0;
    auto take = [&](size_t bytes) -> void* {
        void* p = ws + off;
        off += (bytes + 255) & ~(size_t)255;
        return p;
    };
    int*    flag   = (int*)   take(4);
    float*  dinv   = (float*) take((size_t)N * 4);
    int*    cnt    = (int*)   take((size_t)N * 4);
    int*    rowptr = (int*)   take((size_t)(N + 1) * 4);
    float2* ep     = (float2*)take((size_t)E * 8);
    float*  h1     = (float*) take((size_t)N * HID * 4);
    float*  agg1   = (float*) take((size_t)N * HID * 4);
    float*  h2     = h1;   // h1 dead after AGG1; reuse for layer-2 transform

    int gN  = (N + 255) / 256;
    int gE  = (E + 255) / 256;
    int gM  = (N + 63) / 64;
    int gA1 = (N + 7) / 8;
    int gA2 = (N + 15) / 16;

    k_detect   <<<1,   64,  0, stream>>>(e32, flag);
    k_init     <<<gN,  256, 0, stream>>>(cnt, N);
    k_count    <<<gE,  256, 0, stream>>>(e32, flag, cnt, E);
    k_scan     <<<1, SCAN_T, 0, stream>>>(cnt, rowptr, N, E);
    k_dinv_zero<<<gN,  256, 0, stream>>>(cnt, dinv, cnt, N);
    k_fill     <<<gE,  256, 0, stream>>>(e32, flag, rowptr, cnt, dinv, ep, E);
    k_gemm1    <<<gM,  256, 0, stream>>>(x, W1, h1, N);
    k_agg1     <<<gA1, 256, 0, stream>>>(h1, dinv, rowptr, ep, b1, agg1, N);
    k_gemm2    <<<gM,  256, 0, stream>>>(agg1, W2, h2, N);
    k_agg2     <<<gA2, 256, 0, stream>>>(h2, dinv, rowptr, ep, b2, out, N);
}

// Round 4
// 337.936 us; speedup vs baseline: 1.5913x; 1.2236x over previous
//
#include <hip/hip_runtime.h>

// ---------------------------------------------------------------------------
// 2-layer GCN on MI355X.  Pipeline (10 launches):
//   init(+dtype detect) -> count deg -> scan1/scan2/scan3 (device-wide CSR
//   rowptr + dinv + cursor zero) -> fill CSR w/ packed (src, dinv[src])
//   -> GEMM1 (x@W1) -> AGG1 (gather, +b1, relu)
//   -> GEMM2 (h@W2) -> AGG2 (gather, +b2) -> d_out
// All fp32 (no fp32 MFMA on CDNA4; bf16 risky vs 1e-2 absmax threshold).
// Round-2: agg kernels restructured for MLP (half/quarter-wave per node,
//   float4 lanes, 4-wide edge unroll, packed per-edge meta) -- 537->413 us.
// Round-4: single-block k_scan (76 us, 1 CU, latency-bound) replaced by
//   3-phase device-wide scan (~8 us); dinv/cursor fused into scan3; detect
//   fused into init.
// ---------------------------------------------------------------------------

#define SCB 256            // scan block threads
#define SCE 8              // elements per thread
#define SCTILE (SCB * SCE) // 2048 elements per block

// init: zero cnt; block 0 wave 0 also detects int64-vs-int32 edge layout
// (odd int32 words all zero => int64; values < 2^31 so low word suffices).
__global__ void k_init(const int* __restrict__ e32, int* __restrict__ flag,
                       int* __restrict__ cnt, int n) {
    int i = blockIdx.x * blockDim.x + threadIdx.x;
    if (i < n) cnt[i] = 0;
    if (blockIdx.x == 0 && threadIdx.x < 64) {
        int v = e32[2 * threadIdx.x + 1];
        unsigned long long ball = __ballot(v == 0);
        if (threadIdx.x == 0) flag[0] = (ball == ~0ull) ? 1 : 0;
    }
}

__device__ __forceinline__ int edge_at(const int* __restrict__ e32, long long idx, int is64) {
    return is64 ? e32[2 * idx] : e32[(int)idx];
}

__global__ void k_count(const int* __restrict__ e32, const int* __restrict__ flag,
                        int* __restrict__ cnt, int E) {
    int is64 = flag[0];
    int e = blockIdx.x * blockDim.x + threadIdx.x;
    if (e < E) {
        int d = edge_at(e32, (long long)E + e, is64);   // dst row = second half
        atomicAdd(&cnt[d], 1);
    }
}

// scan1: per-block sum of a 2048-element tile of cnt.
__global__ __launch_bounds__(SCB) void k_scan1(const int* __restrict__ cnt,
                                               int* __restrict__ blksum, int n) {
    __shared__ int red[SCB];
    int t = threadIdx.x;
    int base = blockIdx.x * SCTILE + t * SCE;
    int s = 0;
    if (base + SCE <= n) {
        int4 a = *reinterpret_cast<const int4*>(&cnt[base]);
        int4 b = *reinterpret_cast<const int4*>(&cnt[base + 4]);
        s = a.x + a.y + a.z + a.w + b.x + b.y + b.z + b.w;
    } else {
        for (int i = 0; i < SCE; ++i) { int idx = base + i; if (idx < n) s += cnt[idx]; }
    }
    red[t] = s;
    __syncthreads();
    for (int off = SCB / 2; off > 0; off >>= 1) {
        if (t < off) red[t] += red[t + off];
        __syncthreads();
    }
    if (t == 0) blksum[blockIdx.x] = red[0];
}

// scan2: one block turns blksum (nb <= 256 entries) into exclusive offsets.
__global__ __launch_bounds__(SCB) void k_scan2(int* __restrict__ blksum, int nb) {
    __shared__ int red[SCB];
    int t = threadIdx.x;
    int v = (t < nb) ? blksum[t] : 0;
    red[t] = v;
    __syncthreads();
    for (int off = 1; off < SCB; off <<= 1) {          // Hillis-Steele inclusive
        int x = (t >= off) ? red[t - off] : 0;
        __syncthreads();
        red[t] += x;
        __syncthreads();
    }
    if (t < nb) blksum[t] = red[t] - v;                // exclusive, in place
}

// scan3: block-local exclusive scan + global offset -> rowptr; fused
// dinv = rsqrt(1+cnt) and cursor zeroing (cnt reused as cursor by k_fill).
__global__ __launch_bounds__(SCB) void k_scan3(const int* __restrict__ cnt,
                                               const int* __restrict__ blksum,
                                               int* __restrict__ rowptr,
                                               float* __restrict__ dinv,
                                               int* __restrict__ cursor,
                                               int n, int E) {
    __shared__ int red[SCB];
    int t = threadIdx.x;
    int base = blockIdx.x * SCTILE + t * SCE;
    int v[SCE];
    int s = 0;
    if (base + SCE <= n) {
        int4 a = *reinterpret_cast<const int4*>(&cnt[base]);
        int4 b = *reinterpret_cast<const int4*>(&cnt[base + 4]);
        v[0] = a.x; v[1] = a.y; v[2] = a.z; v[3] = a.w;
        v[4] = b.x; v[5] = b.y; v[6] = b.z; v[7] = b.w;
        s = v[0] + v[1] + v[2] + v[3] + v[4] + v[5] + v[6] + v[7];
    } else {
        for (int i = 0; i < SCE; ++i) {
            int idx = base + i;
            v[i] = (idx < n) ? cnt[idx] : 0;
            s += v[i];
        }
    }
    red[t] = s;
    __syncthreads();
    for (int off = 1; off < SCB; off <<= 1) {          // Hillis-Steele inclusive
        int x = (t >= off) ? red[t - off] : 0;
        __syncthreads();
        red[t] += x;
        __syncthreads();
    }
    int run = red[t] - s + blksum[blockIdx.x];         // exclusive base
    #pragma unroll
    for (int i = 0; i < SCE; ++i) {
        int idx = base + i;
        if (idx < n) {
            rowptr[idx] = run;
            dinv[idx]   = rsqrtf(1.0f + (float)v[i]);  // self-loop included
            cursor[idx] = 0;
            run += v[i];
        }
    }
    if (blockIdx.x == 0 && t == 0) rowptr[n] = E;
}

// CSR fill with packed metadata: ep[pos] = { bitcast(src), dinv[src] }.
__global__ void k_fill(const int* __restrict__ e32, const int* __restrict__ flag,
                       const int* __restrict__ rowptr, int* __restrict__ cursor,
                       const float* __restrict__ dinv, float2* __restrict__ ep, int E) {
    int is64 = flag[0];
    int e = blockIdx.x * blockDim.x + threadIdx.x;
    if (e < E) {
        int s = edge_at(e32, e, is64);
        int d = edge_at(e32, (long long)E + e, is64);
        int pos = rowptr[d] + atomicAdd(&cursor[d], 1);
        ep[pos] = make_float2(__int_as_float(s), dinv[s]);
    }
}

// GEMM1: X[n,256] @ W[256,128] -> H[n,128].  BM=64, BN=128, BK=32, 256 thr.
__global__ __launch_bounds__(256) void k_gemm1(const float* __restrict__ X,
                                               const float* __restrict__ W,
                                               float* __restrict__ H, int n) {
    __shared__ float As[32][68];    // transposed [k][m]; 272 B stride (16B-aligned)
    __shared__ float Bs[32][128];
    int t = threadIdx.x;
    int ty = t >> 4, tx = t & 15;   // 16 x 16 thread grid, each 4 rows x 8 cols
    int row0 = blockIdx.x * 64;
    float acc[4][8] = {};
    for (int k0 = 0; k0 < 256; k0 += 32) {
        {   // A tile: 64 rows x 32 k, 2 x float4 per thread
            int r = t >> 3;            // 0..31
            int kk = (t & 7) * 4;      // 0..28
            #pragma unroll
            for (int p = 0; p < 2; ++p) {
                int rr = r + p * 32;
                int grow = row0 + rr;
                float4 v = {0.f, 0.f, 0.f, 0.f};
                if (grow < n) v = *reinterpret_cast<const float4*>(&X[(size_t)grow * 256 + k0 + kk]);
                As[kk + 0][rr] = v.x; As[kk + 1][rr] = v.y;
                As[kk + 2][rr] = v.z; As[kk + 3][rr] = v.w;
            }
        }
        {   // B tile: 32 k x 128 cols, 4 x float4 per thread
            int kk = t >> 5;           // 0..7
            int c  = (t & 31) * 4;     // 0..124
            #pragma unroll
            for (int p = 0; p < 4; ++p) {
                int krow = kk + p * 8;
                *reinterpret_cast<float4*>(&Bs[krow][c]) =
                    *reinterpret_cast<const float4*>(&W[(k0 + krow) * 128 + c]);
            }
        }
        __syncthreads();
        #pragma unroll
        for (int k = 0; k < 32; ++k) {
            float4 av = *reinterpret_cast<const float4*>(&As[k][ty * 4]);
            float a[4] = {av.x, av.y, av.z, av.w};
            float4 b0 = *reinterpret_cast<const float4*>(&Bs[k][tx * 8]);
            float4 b1 = *reinterpret_cast<const float4*>(&Bs[k][tx * 8 + 4]);
            float b[8] = {b0.x, b0.y, b0.z, b0.w, b1.x, b1.y, b1.z, b1.w};
            #pragma unroll
            for (int i = 0; i < 4; ++i)
                #pragma unroll
                for (int j = 0; j < 8; ++j)
                    acc[i][j] += a[i] * b[j];
        }
        __syncthreads();
    }
    #pragma unroll
    for (int i = 0; i < 4; ++i) {
        int grow = row0 + ty * 4 + i;
        if (grow < n) {
            float4 o0 = {acc[i][0], acc[i][1], acc[i][2], acc[i][3]};
            float4 o1 = {acc[i][4], acc[i][5], acc[i][6], acc[i][7]};
            *reinterpret_cast<float4*>(&H[(size_t)grow * 128 + tx * 8])     = o0;
            *reinterpret_cast<float4*>(&H[(size_t)grow * 128 + tx * 8 + 4]) = o1;
        }
    }
}

// AGG1: half-wave (32 lanes x float4) per node, 128 features.
// out = relu(dn*(h[n]*dn + sum_s h[s]*dinv[s]) + b1)
__global__ __launch_bounds__(256) void k_agg1(const float* __restrict__ H,
                                              const float* __restrict__ dinv,
                                              const int* __restrict__ rowptr,
                                              const float2* __restrict__ ep,
                                              const float* __restrict__ b1,
                                              float* __restrict__ O, int n) {
    int half = threadIdx.x >> 5;        // 0..7
    int lane = threadIdx.x & 31;
    int node = blockIdx.x * 8 + half;
    if (node >= n) return;
    int f = lane * 4;
    float dn = dinv[node];
    float4 acc = *reinterpret_cast<const float4*>(&H[(size_t)node * 128 + f]);
    acc.x *= dn; acc.y *= dn; acc.z *= dn; acc.w *= dn;
    int lo = rowptr[node], hi = rowptr[node + 1];
    int e = lo;
    for (; e + 4 <= hi; e += 4) {       // 4 row loads in flight per half-wave
        float2 m0 = ep[e + 0], m1 = ep[e + 1], m2 = ep[e + 2], m3 = ep[e + 3];
        const float4 v0 = *reinterpret_cast<const float4*>(&H[(size_t)__float_as_int(m0.x) * 128 + f]);
        const float4 v1 = *reinterpret_cast<const float4*>(&H[(size_t)__float_as_int(m1.x) * 128 + f]);
        const float4 v2 = *reinterpret_cast<const float4*>(&H[(size_t)__float_as_int(m2.x) * 128 + f]);
        const float4 v3 = *reinterpret_cast<const float4*>(&H[(size_t)__float_as_int(m3.x) * 128 + f]);
        acc.x += v0.x * m0.y + v1.x * m1.y + v2.x * m2.y + v3.x * m3.y;
        acc.y += v0.y * m0.y + v1.y * m1.y + v2.y * m2.y + v3.y * m3.y;
        acc.z += v0.z * m0.y + v1.z * m1.y + v2.z * m2.y + v3.z * m3.y;
        acc.w += v0.w * m0.y + v1.w * m1.y + v2.w * m2.y + v3.w * m3.y;
    }
    for (; e < hi; ++e) {
        float2 m = ep[e];
        const float4 v = *reinterpret_cast<const float4*>(&H[(size_t)__float_as_int(m.x) * 128 + f]);
        acc.x += v.x * m.y; acc.y += v.y * m.y;
        acc.z += v.z * m.y; acc.w += v.w * m.y;
    }
    float4 bv = *reinterpret_cast<const float4*>(&b1[f]);
    acc.x = fmaxf(acc.x * dn + bv.x, 0.f);
    acc.y = fmaxf(acc.y * dn + bv.y, 0.f);
    acc.z = fmaxf(acc.z * dn + bv.z, 0.f);
    acc.w = fmaxf(acc.w * dn + bv.w, 0.f);
    *reinterpret_cast<float4*>(&O[(size_t)node * 128 + f]) = acc;
}

// GEMM2: A[n,128] @ W2[128,64] -> H[n,64].  W2 fully LDS-resident.
__global__ __launch_bounds__(256) void k_gemm2(const float* __restrict__ A,
                                               const float* __restrict__ W,
                                               float* __restrict__ H, int n) {
    __shared__ float As[32][68];
    __shared__ float Bs[128][64];
    int t = threadIdx.x;
    int ty = t >> 4, tx = t & 15;   // each thread: 4 rows x 4 cols
    int row0 = blockIdx.x * 64;
    {   // load all of W2: 8192 floats = 2048 float4
        const float4* Wv = reinterpret_cast<const float4*>(W);
        float4* Bv = reinterpret_cast<float4*>(&Bs[0][0]);
        for (int i = t; i < 2048; i += 256) Bv[i] = Wv[i];
    }
    float acc[4][4] = {};
    for (int k0 = 0; k0 < 128; k0 += 32) {
        __syncthreads();    // protect previous iter's As reads (and Bs load, iter 0)
        {
            int r = t >> 3;
            int kk = (t & 7) * 4;
            #pragma unroll
            for (int p = 0; p < 2; ++p) {
                int rr = r + p * 32;
                int grow = row0 + rr;
                float4 v = {0.f, 0.f, 0.f, 0.f};
                if (grow < n) v = *reinterpret_cast<const float4*>(&A[(size_t)grow * 128 + k0 + kk]);
                As[kk + 0][rr] = v.x; As[kk + 1][rr] = v.y;
                As[kk + 2][rr] = v.z; As[kk + 3][rr] = v.w;
            }
        }
        __syncthreads();
        #pragma unroll
        for (int k = 0; k < 32; ++k) {
            float4 av = *reinterpret_cast<const float4*>(&As[k][ty * 4]);
            float a[4] = {av.x, av.y, av.z, av.w};
            float4 b = *reinterpret_cast<const float4*>(&Bs[k0 + k][tx * 4]);
            #pragma unroll
            for (int i = 0; i < 4; ++i) {
                acc[i][0] += a[i] * b.x; acc[i][1] += a[i] * b.y;
                acc[i][2] += a[i] * b.z; acc[i][3] += a[i] * b.w;
            }
        }
    }
    #pragma unroll
    for (int i = 0; i < 4; ++i) {
        int grow = row0 + ty * 4 + i;
        if (grow < n) {
            float4 o = {acc[i][0], acc[i][1], acc[i][2], acc[i][3]};
            *reinterpret_cast<float4*>(&H[(size_t)grow * 64 + tx * 4]) = o;
        }
    }
}

// AGG2: quarter-wave (16 lanes x float4) per node, 64 features, += b2 -> d_out.
__global__ __launch_bounds__(256) void k_agg2(const float* __restrict__ H,
                                              const float* __restrict__ dinv,
                                              const int* __restrict__ rowptr,
                                              const float2* __restrict__ ep,
                                              const float* __restrict__ b2,
                                              float* __restrict__ O, int n) {
    int q    = threadIdx.x >> 4;        // 0..15
    int lane = threadIdx.x & 15;
    int node = blockIdx.x * 16 + q;
    if (node >= n) return;
    int f = lane * 4;
    float dn = dinv[node];
    float4 acc = *reinterpret_cast<const float4*>(&H[(size_t)node * 64 + f]);
    acc.x *= dn; acc.y *= dn; acc.z *= dn; acc.w *= dn;
    int lo = rowptr[node], hi = rowptr[node + 1];
    int e = lo;
    for (; e + 4 <= hi; e += 4) {
        float2 m0 = ep[e + 0], m1 = ep[e + 1], m2 = ep[e + 2], m3 = ep[e + 3];
        const float4 v0 = *reinterpret_cast<const float4*>(&H[(size_t)__float_as_int(m0.x) * 64 + f]);
        const float4 v1 = *reinterpret_cast<const float4*>(&H[(size_t)__float_as_int(m1.x) * 64 + f]);
        const float4 v2 = *reinterpret_cast<const float4*>(&H[(size_t)__float_as_int(m2.x) * 64 + f]);
        const float4 v3 = *reinterpret_cast<const float4*>(&H[(size_t)__float_as_int(m3.x) * 64 + f]);
        acc.x += v0.x * m0.y + v1.x * m1.y + v2.x * m2.y + v3.x * m3.y;
        acc.y += v0.y * m0.y + v1.y * m1.y + v2.y * m2.y + v3.y * m3.y;
        acc.z += v0.z * m0.y + v1.z * m1.y + v2.z * m2.y + v3.z * m3.y;
        acc.w += v0.w * m0.y + v1.w * m1.y + v2.w * m2.y + v3.w * m3.y;
    }
    for (; e < hi; ++e) {
        float2 m = ep[e];
        const float4 v = *reinterpret_cast<const float4*>(&H[(size_t)__float_as_int(m.x) * 64 + f]);
        acc.x += v.x * m.y; acc.y += v.y * m.y;
        acc.z += v.z * m.y; acc.w += v.w * m.y;
    }
    float4 bv = *reinterpret_cast<const float4*>(&b2[f]);
    acc.x = acc.x * dn + bv.x;
    acc.y = acc.y * dn + bv.y;
    acc.z = acc.z * dn + bv.z;
    acc.w = acc.w * dn + bv.w;
    *reinterpret_cast<float4*>(&O[(size_t)node * 64 + f]) = acc;
}

extern "C" void kernel_launch(void* const* d_in, const int* in_sizes, int n_in,
                              void* d_out, int out_size, void* d_ws, size_t ws_size,
                              hipStream_t stream) {
    const float* x   = (const float*)d_in[0];
    const int*   e32 = (const int*)d_in[1];
    const float* W1  = (const float*)d_in[2];
    const float* b1  = (const float*)d_in[3];
    const float* W2  = (const float*)d_in[4];
    const float* b2  = (const float*)d_in[5];
    float* out = (float*)d_out;

    const int HID  = in_sizes[3];           // 128
    const int FIN  = in_sizes[2] / HID;     // 256
    const int N    = in_sizes[0] / FIN;     // 50000
    const int E    = in_sizes[1] / 2;       // 800000
    (void)n_in; (void)out_size; (void)ws_size;

    char* ws = (char*)d_ws;
    size_t off = 0;
    auto take = [&](size_t bytes) -> void* {
        void* p = ws + off;
        off += (bytes + 255) & ~(size_t)255;
        return p;
    };
    int*    flag   = (int*)   take(4);
    float*  dinv   = (float*) take((size_t)N * 4);
    int*    cnt    = (int*)   take((size_t)N * 4);
    int*    rowptr = (int*)   take((size_t)(N + 1) * 4);
    int*    blksum = (int*)   take((size_t)SCB * 4);
    float2* ep     = (float2*)take((size_t)E * 8);
    float*  h1     = (float*) take((size_t)N * HID * 4);
    float*  agg1   = (float*) take((size_t)N * HID * 4);
    float*  h2     = h1;   // h1 dead after AGG1; reuse for layer-2 transform

    int gN  = (N + 255) / 256;
    int gE  = (E + 255) / 256;
    int gS  = (N + SCTILE - 1) / SCTILE;    // scan blocks (25 @ N=50000)
    int gM  = (N + 63) / 64;
    int gA1 = (N + 7) / 8;
    int gA2 = (N + 15) / 16;

    k_init  <<<gN,  256, 0, stream>>>(e32, flag, cnt, N);
    k_count <<<gE,  256, 0, stream>>>(e32, flag, cnt, E);
    k_scan1 <<<gS,  SCB, 0, stream>>>(cnt, blksum, N);
    k_scan2 <<<1,   SCB, 0, stream>>>(blksum, gS);
    k_scan3 <<<gS,  SCB, 0, stream>>>(cnt, blksum, rowptr, dinv, cnt, N, E);
    k_fill  <<<gE,  256, 0, stream>>>(e32, flag, rowptr, cnt, dinv, ep, E);
    k_gemm1 <<<gM,  256, 0, stream>>>(x, W1, h1, N);
    k_agg1  <<<gA1, 256, 0, stream>>>(h1, dinv, rowptr, ep, b1, agg1, N);
    k_gemm2 <<<gM,  256, 0, stream>>>(agg1, W2, h2, N);
    k_agg2  <<<gA2, 256, 0, stream>>>(h2, dinv, rowptr, ep, b2, out, N);
}

// Round 5
// 303.227 us; speedup vs baseline: 1.7734x; 1.1145x over previous
//
#include <hip/hip_runtime.h>

// ---------------------------------------------------------------------------
// 2-layer GCN on MI355X.  Pipeline (12 launches):
//   wprep(W1) -> wprep(W2) -> init(+dtype detect) -> count -> scan1/2/3
//   -> fill CSR (packed src,dinv) -> GEMM1 (MFMA split-bf16) -> AGG1
//   -> GEMM2 (MFMA split-bf16) -> AGG2 -> d_out
// Round-2: agg MLP restructure (537->413).  Round-4: device-wide scan
//   (413->338).  Round-5: GEMMs moved to matrix cores via split-bf16
//   (x ~ xh+xl, W ~ wh+wl; AhBh+AlBh+AhBl; err ~1e-4 << 1e-2 threshold).
//   fp32 vector GEMM was 70.7 us @ 33% VALUBusy, latency-bound.
// ---------------------------------------------------------------------------

typedef __attribute__((ext_vector_type(8))) short bf16x8;
typedef __attribute__((ext_vector_type(4))) float f32x4;

__device__ __forceinline__ unsigned short f2bf_rne(float f) {
    unsigned u = __float_as_uint(f);
    u = u + 0x7fffu + ((u >> 16) & 1u);          // round-to-nearest-even
    return (unsigned short)(u >> 16);
}

// One-time W transform: W[K][N] fp32 -> Wt_hi/Wt_lo[N][K] bf16 (hi + residual).
__global__ void k_wprep(const float* __restrict__ W, unsigned short* __restrict__ Wt_hi,
                        unsigned short* __restrict__ Wt_lo, int K, int N) {
    int id = blockIdx.x * blockDim.x + threadIdx.x;
    if (id < K * N) {
        int k = id / N, nn = id - k * N;         // coalesced read of W
        float f = W[id];
        unsigned short h = f2bf_rne(f);
        float hf = __uint_as_float((unsigned)h << 16);
        Wt_hi[(size_t)nn * K + k] = h;
        Wt_lo[(size_t)nn * K + k] = f2bf_rne(f - hf);
    }
}

// init: zero cnt; block 0 wave 0 also detects int64-vs-int32 edge layout.
__global__ void k_init(const int* __restrict__ e32, int* __restrict__ flag,
                       int* __restrict__ cnt, int n) {
    int i = blockIdx.x * blockDim.x + threadIdx.x;
    if (i < n) cnt[i] = 0;
    if (blockIdx.x == 0 && threadIdx.x < 64) {
        int v = e32[2 * threadIdx.x + 1];
        unsigned long long ball = __ballot(v == 0);
        if (threadIdx.x == 0) flag[0] = (ball == ~0ull) ? 1 : 0;
    }
}

__device__ __forceinline__ int edge_at(const int* __restrict__ e32, long long idx, int is64) {
    return is64 ? e32[2 * idx] : e32[(int)idx];
}

__global__ void k_count(const int* __restrict__ e32, const int* __restrict__ flag,
                        int* __restrict__ cnt, int E) {
    int is64 = flag[0];
    int e = blockIdx.x * blockDim.x + threadIdx.x;
    if (e < E) {
        int d = edge_at(e32, (long long)E + e, is64);   // dst row = second half
        atomicAdd(&cnt[d], 1);
    }
}

#define SCB 256            // scan block threads
#define SCE 8              // elements per thread
#define SCTILE (SCB * SCE) // 2048 elements per block

__global__ __launch_bounds__(SCB) void k_scan1(const int* __restrict__ cnt,
                                               int* __restrict__ blksum, int n) {
    __shared__ int red[SCB];
    int t = threadIdx.x;
    int base = blockIdx.x * SCTILE + t * SCE;
    int s = 0;
    if (base + SCE <= n) {
        int4 a = *reinterpret_cast<const int4*>(&cnt[base]);
        int4 b = *reinterpret_cast<const int4*>(&cnt[base + 4]);
        s = a.x + a.y + a.z + a.w + b.x + b.y + b.z + b.w;
    } else {
        for (int i = 0; i < SCE; ++i) { int idx = base + i; if (idx < n) s += cnt[idx]; }
    }
    red[t] = s;
    __syncthreads();
    for (int off = SCB / 2; off > 0; off >>= 1) {
        if (t < off) red[t] += red[t + off];
        __syncthreads();
    }
    if (t == 0) blksum[blockIdx.x] = red[0];
}

__global__ __launch_bounds__(SCB) void k_scan2(int* __restrict__ blksum, int nb) {
    __shared__ int red[SCB];
    int t = threadIdx.x;
    int v = (t < nb) ? blksum[t] : 0;
    red[t] = v;
    __syncthreads();
    for (int off = 1; off < SCB; off <<= 1) {          // Hillis-Steele inclusive
        int x = (t >= off) ? red[t - off] : 0;
        __syncthreads();
        red[t] += x;
        __syncthreads();
    }
    if (t < nb) blksum[t] = red[t] - v;                // exclusive, in place
}

// scan3: rowptr + fused dinv + cursor zero.
__global__ __launch_bounds__(SCB) void k_scan3(const int* __restrict__ cnt,
                                               const int* __restrict__ blksum,
                                               int* __restrict__ rowptr,
                                               float* __restrict__ dinv,
                                               int* __restrict__ cursor,
                                               int n, int E) {
    __shared__ int red[SCB];
    int t = threadIdx.x;
    int base = blockIdx.x * SCTILE + t * SCE;
    int v[SCE];
    int s = 0;
    if (base + SCE <= n) {
        int4 a = *reinterpret_cast<const int4*>(&cnt[base]);
        int4 b = *reinterpret_cast<const int4*>(&cnt[base + 4]);
        v[0] = a.x; v[1] = a.y; v[2] = a.z; v[3] = a.w;
        v[4] = b.x; v[5] = b.y; v[6] = b.z; v[7] = b.w;
        s = v[0] + v[1] + v[2] + v[3] + v[4] + v[5] + v[6] + v[7];
    } else {
        for (int i = 0; i < SCE; ++i) {
            int idx = base + i;
            v[i] = (idx < n) ? cnt[idx] : 0;
            s += v[i];
        }
    }
    red[t] = s;
    __syncthreads();
    for (int off = 1; off < SCB; off <<= 1) {
        int x = (t >= off) ? red[t - off] : 0;
        __syncthreads();
        red[t] += x;
        __syncthreads();
    }
    int run = red[t] - s + blksum[blockIdx.x];
    #pragma unroll
    for (int i = 0; i < SCE; ++i) {
        int idx = base + i;
        if (idx < n) {
            rowptr[idx] = run;
            dinv[idx]   = rsqrtf(1.0f + (float)v[i]);  // self-loop included
            cursor[idx] = 0;
            run += v[i];
        }
    }
    if (blockIdx.x == 0 && t == 0) rowptr[n] = E;
}

// CSR fill with packed metadata: ep[pos] = { bitcast(src), dinv[src] }.
__global__ void k_fill(const int* __restrict__ e32, const int* __restrict__ flag,
                       const int* __restrict__ rowptr, int* __restrict__ cursor,
                       const float* __restrict__ dinv, float2* __restrict__ ep, int E) {
    int is64 = flag[0];
    int e = blockIdx.x * blockDim.x + threadIdx.x;
    if (e < E) {
        int s = edge_at(e32, e, is64);
        int d = edge_at(e32, (long long)E + e, is64);
        int pos = rowptr[d] + atomicAdd(&cursor[d], 1);
        ep[pos] = make_float2(__int_as_float(s), dinv[s]);
    }
}

// Split-bf16 MFMA GEMM: H[n,N] = A[n,K] @ W[K,N] via Wt_hi/lo[N][K].
// BM=64, 4 waves; wave w owns rows w*16..w*16+15 x all N cols (N/16 tiles).
// m89-verified 16x16x32 layouts: a[j]=A[l&15][(l>>4)*8+j], b[j]=B[(l>>4)*8+j][l&15],
// d[i]=D[(l>>4)*4+i][l&15].
template<int K, int N>
__global__ __launch_bounds__(256) void k_gemm_mfma(const float* __restrict__ A,
        const unsigned short* __restrict__ Wt_hi, const unsigned short* __restrict__ Wt_lo,
        float* __restrict__ H, int n) {
    constexpr int NT  = N / 16;     // n-tiles per wave
    constexpr int LDA = 40;         // padded LDS row stride in bf16 (80 B, <=2-way conflicts)
    __shared__ unsigned short Ah[64 * LDA], Al[64 * LDA];
    __shared__ unsigned short Wh[N * LDA],  Wl[N * LDA];
    int t = threadIdx.x;
    int w = t >> 6, l = t & 63;
    int row0 = blockIdx.x * 64;
    int lrow = l & 15, lk = (l >> 4) * 8;
    f32x4 acc[NT];
    #pragma unroll
    for (int i = 0; i < NT; ++i) acc[i] = (f32x4){0.f, 0.f, 0.f, 0.f};

    for (int k0 = 0; k0 < K; k0 += 32) {
        {   // stage A tile [64][32] fp32 -> hi/lo bf16; thread t: row t>>2, k (t&3)*8
            int r = t >> 2, kk = (t & 3) * 8;
            int grow = row0 + r;
            float v[8] = {0.f, 0.f, 0.f, 0.f, 0.f, 0.f, 0.f, 0.f};
            if (grow < n) {
                float4 x0 = *reinterpret_cast<const float4*>(&A[(size_t)grow * K + k0 + kk]);
                float4 x1 = *reinterpret_cast<const float4*>(&A[(size_t)grow * K + k0 + kk + 4]);
                v[0] = x0.x; v[1] = x0.y; v[2] = x0.z; v[3] = x0.w;
                v[4] = x1.x; v[5] = x1.y; v[6] = x1.z; v[7] = x1.w;
            }
            unsigned short h8[8], l8[8];
            #pragma unroll
            for (int i = 0; i < 8; ++i) {
                unsigned short h = f2bf_rne(v[i]);
                h8[i] = h;
                l8[i] = f2bf_rne(v[i] - __uint_as_float((unsigned)h << 16));
            }
            *reinterpret_cast<bf16x8*>(&Ah[r * LDA + kk]) = *reinterpret_cast<const bf16x8*>(h8);
            *reinterpret_cast<bf16x8*>(&Al[r * LDA + kk]) = *reinterpret_cast<const bf16x8*>(l8);
        }
        // stage W k-slice: Wt[nn][k0..k0+32] -> Wh/Wl, 16B chunks
        for (int c = t; c < N * 4; c += 256) {
            int nn = c >> 2, part = (c & 3) * 8;
            *reinterpret_cast<bf16x8*>(&Wh[nn * LDA + part]) =
                *reinterpret_cast<const bf16x8*>(&Wt_hi[(size_t)nn * K + k0 + part]);
            *reinterpret_cast<bf16x8*>(&Wl[nn * LDA + part]) =
                *reinterpret_cast<const bf16x8*>(&Wt_lo[(size_t)nn * K + k0 + part]);
        }
        __syncthreads();
        bf16x8 ah = *reinterpret_cast<const bf16x8*>(&Ah[(w * 16 + lrow) * LDA + lk]);
        bf16x8 al = *reinterpret_cast<const bf16x8*>(&Al[(w * 16 + lrow) * LDA + lk]);
        #pragma unroll
        for (int tt = 0; tt < NT; ++tt) {
            bf16x8 bh = *reinterpret_cast<const bf16x8*>(&Wh[(tt * 16 + lrow) * LDA + lk]);
            bf16x8 bl = *reinterpret_cast<const bf16x8*>(&Wl[(tt * 16 + lrow) * LDA + lk]);
            acc[tt] = __builtin_amdgcn_mfma_f32_16x16x32_bf16(ah, bh, acc[tt], 0, 0, 0);
            acc[tt] = __builtin_amdgcn_mfma_f32_16x16x32_bf16(al, bh, acc[tt], 0, 0, 0);
            acc[tt] = __builtin_amdgcn_mfma_f32_16x16x32_bf16(ah, bl, acc[tt], 0, 0, 0);
        }
        __syncthreads();
    }
    #pragma unroll
    for (int tt = 0; tt < NT; ++tt) {
        #pragma unroll
        for (int i = 0; i < 4; ++i) {
            int grow = row0 + w * 16 + (l >> 4) * 4 + i;
            if (grow < n) H[(size_t)grow * N + tt * 16 + lrow] = acc[tt][i];
        }
    }
}

// AGG1: half-wave (32 lanes x float4) per node, 128 features.
__global__ __launch_bounds__(256) void k_agg1(const float* __restrict__ H,
                                              const float* __restrict__ dinv,
                                              const int* __restrict__ rowptr,
                                              const float2* __restrict__ ep,
                                              const float* __restrict__ b1,
                                              float* __restrict__ O, int n) {
    int half = threadIdx.x >> 5;
    int lane = threadIdx.x & 31;
    int node = blockIdx.x * 8 + half;
    if (node >= n) return;
    int f = lane * 4;
    float dn = dinv[node];
    float4 acc = *reinterpret_cast<const float4*>(&H[(size_t)node * 128 + f]);
    acc.x *= dn; acc.y *= dn; acc.z *= dn; acc.w *= dn;
    int lo = rowptr[node], hi = rowptr[node + 1];
    int e = lo;
    for (; e + 4 <= hi; e += 4) {       // 4 row loads in flight per half-wave
        float2 m0 = ep[e + 0], m1 = ep[e + 1], m2 = ep[e + 2], m3 = ep[e + 3];
        const float4 v0 = *reinterpret_cast<const float4*>(&H[(size_t)__float_as_int(m0.x) * 128 + f]);
        const float4 v1 = *reinterpret_cast<const float4*>(&H[(size_t)__float_as_int(m1.x) * 128 + f]);
        const float4 v2 = *reinterpret_cast<const float4*>(&H[(size_t)__float_as_int(m2.x) * 128 + f]);
        const float4 v3 = *reinterpret_cast<const float4*>(&H[(size_t)__float_as_int(m3.x) * 128 + f]);
        acc.x += v0.x * m0.y + v1.x * m1.y + v2.x * m2.y + v3.x * m3.y;
        acc.y += v0.y * m0.y + v1.y * m1.y + v2.y * m2.y + v3.y * m3.y;
        acc.z += v0.z * m0.y + v1.z * m1.y + v2.z * m2.y + v3.z * m3.y;
        acc.w += v0.w * m0.y + v1.w * m1.y + v2.w * m2.y + v3.w * m3.y;
    }
    for (; e < hi; ++e) {
        float2 m = ep[e];
        const float4 v = *reinterpret_cast<const float4*>(&H[(size_t)__float_as_int(m.x) * 128 + f]);
        acc.x += v.x * m.y; acc.y += v.y * m.y;
        acc.z += v.z * m.y; acc.w += v.w * m.y;
    }
    float4 bv = *reinterpret_cast<const float4*>(&b1[f]);
    acc.x = fmaxf(acc.x * dn + bv.x, 0.f);
    acc.y = fmaxf(acc.y * dn + bv.y, 0.f);
    acc.z = fmaxf(acc.z * dn + bv.z, 0.f);
    acc.w = fmaxf(acc.w * dn + bv.w, 0.f);
    *reinterpret_cast<float4*>(&O[(size_t)node * 128 + f]) = acc;
}

// AGG2: quarter-wave (16 lanes x float4) per node, 64 features -> d_out.
__global__ __launch_bounds__(256) void k_agg2(const float* __restrict__ H,
                                              const float* __restrict__ dinv,
                                              const int* __restrict__ rowptr,
                                              const float2* __restrict__ ep,
                                              const float* __restrict__ b2,
                                              float* __restrict__ O, int n) {
    int q    = threadIdx.x >> 4;
    int lane = threadIdx.x & 15;
    int node = blockIdx.x * 16 + q;
    if (node >= n) return;
    int f = lane * 4;
    float dn = dinv[node];
    float4 acc = *reinterpret_cast<const float4*>(&H[(size_t)node * 64 + f]);
    acc.x *= dn; acc.y *= dn; acc.z *= dn; acc.w *= dn;
    int lo = rowptr[node], hi = rowptr[node + 1];
    int e = lo;
    for (; e + 4 <= hi; e += 4) {
        float2 m0 = ep[e + 0], m1 = ep[e + 1], m2 = ep[e + 2], m3 = ep[e + 3];
        const float4 v0 = *reinterpret_cast<const float4*>(&H[(size_t)__float_as_int(m0.x) * 64 + f]);
        const float4 v1 = *reinterpret_cast<const float4*>(&H[(size_t)__float_as_int(m1.x) * 64 + f]);
        const float4 v2 = *reinterpret_cast<const float4*>(&H[(size_t)__float_as_int(m2.x) * 64 + f]);
        const float4 v3 = *reinterpret_cast<const float4*>(&H[(size_t)__float_as_int(m3.x) * 64 + f]);
        acc.x += v0.x * m0.y + v1.x * m1.y + v2.x * m2.y + v3.x * m3.y;
        acc.y += v0.y * m0.y + v1.y * m1.y + v2.y * m2.y + v3.y * m3.y;
        acc.z += v0.z * m0.y + v1.z * m1.y + v2.z * m2.y + v3.z * m3.y;
        acc.w += v0.w * m0.y + v1.w * m1.y + v2.w * m2.y + v3.w * m3.y;
    }
    for (; e < hi; ++e) {
        float2 m = ep[e];
        const float4 v = *reinterpret_cast<const float4*>(&H[(size_t)__float_as_int(m.x) * 64 + f]);
        acc.x += v.x * m.y; acc.y += v.y * m.y;
        acc.z += v.z * m.y; acc.w += v.w * m.y;
    }
    float4 bv = *reinterpret_cast<const float4*>(&b2[f]);
    acc.x = acc.x * dn + bv.x;
    acc.y = acc.y * dn + bv.y;
    acc.z = acc.z * dn + bv.z;
    acc.w = acc.w * dn + bv.w;
    *reinterpret_cast<float4*>(&O[(size_t)node * 64 + f]) = acc;
}

extern "C" void kernel_launch(void* const* d_in, const int* in_sizes, int n_in,
                              void* d_out, int out_size, void* d_ws, size_t ws_size,
                              hipStream_t stream) {
    const float* x   = (const float*)d_in[0];
    const int*   e32 = (const int*)d_in[1];
    const float* W1  = (const float*)d_in[2];
    const float* b1  = (const float*)d_in[3];
    const float* W2  = (const float*)d_in[4];
    const float* b2  = (const float*)d_in[5];
    float* out = (float*)d_out;

    const int HID  = in_sizes[3];           // 128
    const int FIN  = in_sizes[2] / HID;     // 256
    const int N    = in_sizes[0] / FIN;     // 50000
    const int E    = in_sizes[1] / 2;       // 800000
    const int OUT  = in_sizes[5];           // 64
    (void)n_in; (void)out_size; (void)ws_size;

    char* ws = (char*)d_ws;
    size_t off = 0;
    auto take = [&](size_t bytes) -> void* {
        void* p = ws + off;
        off += (bytes + 255) & ~(size_t)255;
        return p;
    };
    int*            flag   = (int*)            take(4);
    float*          dinv   = (float*)          take((size_t)N * 4);
    int*            cnt    = (int*)            take((size_t)N * 4);
    int*            rowptr = (int*)            take((size_t)(N + 1) * 4);
    int*            blksum = (int*)            take((size_t)SCB * 4);
    unsigned short* w1h    = (unsigned short*) take((size_t)FIN * HID * 2);
    unsigned short* w1l    = (unsigned short*) take((size_t)FIN * HID * 2);
    unsigned short* w2h    = (unsigned short*) take((size_t)HID * OUT * 2);
    unsigned short* w2l    = (unsigned short*) take((size_t)HID * OUT * 2);
    float2*         ep     = (float2*)         take((size_t)E * 8);
    float*          h1     = (float*)          take((size_t)N * HID * 4);
    float*          agg1   = (float*)          take((size_t)N * HID * 4);
    float*          h2     = h1;   // h1 dead after AGG1; reuse for layer-2 transform

    int gN  = (N + 255) / 256;
    int gE  = (E + 255) / 256;
    int gS  = (N + SCTILE - 1) / SCTILE;    // 25 @ N=50000
    int gM  = (N + 63) / 64;                // 782
    int gA1 = (N + 7) / 8;
    int gA2 = (N + 15) / 16;
    int gW1 = (FIN * HID + 255) / 256;
    int gW2 = (HID * OUT + 255) / 256;

    k_wprep <<<gW1, 256, 0, stream>>>(W1, w1h, w1l, FIN, HID);
    k_wprep <<<gW2, 256, 0, stream>>>(W2, w2h, w2l, HID, OUT);
    k_init  <<<gN,  256, 0, stream>>>(e32, flag, cnt, N);
    k_count <<<gE,  256, 0, stream>>>(e32, flag, cnt, E);
    k_scan1 <<<gS,  SCB, 0, stream>>>(cnt, blksum, N);
    k_scan2 <<<1,   SCB, 0, stream>>>(blksum, gS);
    k_scan3 <<<gS,  SCB, 0, stream>>>(cnt, blksum, rowptr, dinv, cnt, N, E);
    k_fill  <<<gE,  256, 0, stream>>>(e32, flag, rowptr, cnt, dinv, ep, E);
    k_gemm_mfma<256, 128><<<gM, 256, 0, stream>>>(x, w1h, w1l, h1, N);
    k_agg1  <<<gA1, 256, 0, stream>>>(h1, dinv, rowptr, ep, b1, agg1, N);
    k_gemm_mfma<128, 64> <<<gM, 256, 0, stream>>>(agg1, w2h, w2l, h2, N);
    k_agg2  <<<gA2, 256, 0, stream>>>(h2, dinv, rowptr, ep, b2, out, N);
}